// Round 1
// baseline (12837.148 us; speedup 1.0000x reference)
//
#include <hip/hip_runtime.h>
#include <stdint.h>

#define TSTEPS   4096
#define NEG_VAL  -1000000000.0f
#define NWG_SCAN 96
#define G0WG     32
#define RINGN    32

// ---------------- workspace layout (bytes) ----------------
#define GI0_OFF   0                                   // T*1536 f32 = 25165824
#define H1_OFF    (TSTEPS*1536*4)                     // T*512 f32  = 8388608
#define RING0_OFF (H1_OFF + TSTEPS*512*4)             // 32*512*8   = 131072
#define RING1_OFF (RING0_OFF + RINGN*512*8)           // 32*512*8   = 131072
#define ARR_OFF   (RING1_OFF + RINGN*512*8)           // 32*64B     = 2048
#define WS_NEED   ((size_t)ARR_OFF + RINGN*64)

// ---------------- helpers ----------------
static __device__ __forceinline__ unsigned long long ld_a64(const unsigned long long* p){
  return __hip_atomic_load(p, __ATOMIC_RELAXED, __HIP_MEMORY_SCOPE_AGENT);
}
static __device__ __forceinline__ void st_a64(unsigned long long* p, unsigned long long v){
  __hip_atomic_store(p, v, __ATOMIC_RELAXED, __HIP_MEMORY_SCOPE_AGENT);
}
static __device__ __forceinline__ float sigmoidf_(float x){
  return 1.0f / (1.0f + __expf(-x));
}
static __device__ __forceinline__ float tanhf_(float x){
  float ax = fabsf(x);
  float e  = __expf(-2.0f*ax);
  float t  = (1.0f - e) / (1.0f + e);
  return copysignf(t, x);
}

// spin until all 8 ring words (stride 64) carry `want` tag, then deposit values to LDS.
// word layout: hi32 = tag (epoch+1), lo32 = f32 bits. Single 8B atomic store => no tearing.
static __device__ __forceinline__ void spin_to_lds(const unsigned long long* ring, int slot,
                                                   unsigned want, int lane, float* dst,
                                                   long* budget){
  const unsigned long long* bp = ring + (size_t)slot*512 + lane;
  unsigned long long v[8];
  for(;;){
    #pragma unroll
    for (int j=0;j<8;++j) v[j] = ld_a64(bp + j*64);   // 8 parallel loads per retry
    bool ok = true;
    #pragma unroll
    for (int j=0;j<8;++j) ok = ok && ((unsigned)(v[j]>>32) == want);
    if (ok) break;
    if (--(*budget) < 0) break;                        // hang guard (wrong-but-terminates)
  }
  #pragma unroll
  for (int j=0;j<8;++j) dst[j*64+lane] = __uint_as_float((unsigned)v[j]);
}

// ---------------- persistent 2-layer GRU scan ----------------
// 96 WGs x 384 threads. WG 0..31: layer0 (16 h-indices each). WG 32..95: layer1 (8 each).
// Weights live in VGPRs (w[8][8] per thread). h state crosses WGs via epoch-tagged rings.
__global__ __launch_bounds__(384,1) void gru_scan(
    const float* __restrict__ gi0,
    const float* __restrict__ hprev,
    const float* __restrict__ Whh0,
    const float* __restrict__ Wih1,
    const float* __restrict__ Whh1,
    const float* __restrict__ bhh0,
    const float* __restrict__ bih1,
    const float* __restrict__ bhh1,
    float* __restrict__ H1hist,
    unsigned long long* ring0,
    unsigned long long* ring1,
    unsigned* arr,
    float* __restrict__ hnext)
{
  const int wg   = blockIdx.x;
  const int tid  = threadIdx.x;
  const int wave = tid >> 6;
  const int lane = tid & 63;

  __shared__ float hbuf0[512];
  __shared__ float hbuf1[512];
  __shared__ float sc[64];

  long budget = (1L<<22);

  if (wg < G0WG) {
    // ================= layer 0 =================
    const int ibase = wg*16;
    float w[8][8];
    #pragma unroll
    for (int k=0;k<8;++k){
      const int rid = wave*8+k;            // 48 rows: (gate g = rid>>4, i_local = rid&15)
      const int g = rid>>4, il = rid&15;
      const float* wp = Whh0 + ((size_t)(g*512 + ibase + il))*512;
      #pragma unroll
      for (int j=0;j<8;++j) w[k][j] = wp[j*64 + lane];
    }
    float hreg=0.f, br=0.f, bz=0.f, bn_=0.f;
    const int mi = ibase + tid;
    if (tid < 16){
      hreg = hprev[mi];
      br  = bhh0[mi]; bz = bhh0[512+mi]; bn_ = bhh0[1024+mi];
    }
    for (int t=0; t<TSTEPS; ++t){
      float gr=0.f, gz=0.f, gn=0.f;
      if (tid < 16){                        // prefetch precomputed gi0 early
        const float* gp = gi0 + (size_t)t*1536 + mi;
        gr = gp[0]; gz = gp[512]; gn = gp[1024];
      }
      if (wave == 0){
        if (t == 0){
          #pragma unroll
          for (int j=0;j<8;++j) hbuf0[j*64+lane] = hprev[j*64+lane];
        } else {
          spin_to_lds(ring0, (t-1)&(RINGN-1), (unsigned)t, lane, hbuf0, &budget);
        }
      }
      if (tid==0 && t>=16){                 // producer flow control (lag-16, ring 32)
        unsigned* ap = arr + (size_t)((t-16)&(RINGN-1))*16;
        const unsigned expect = (unsigned)NWG_SCAN * (unsigned)(((t-16)>>5)+1);
        while (__hip_atomic_load(ap, __ATOMIC_RELAXED, __HIP_MEMORY_SCOPE_AGENT) < expect){
          if (--budget < 0) break;
        }
      }
      __syncthreads();
      float hj[8];
      #pragma unroll
      for (int j=0;j<8;++j) hj[j] = hbuf0[j*64+lane];
      float acc[8];
      #pragma unroll
      for (int k=0;k<8;++k){
        float a = 0.f;
        #pragma unroll
        for (int j=0;j<8;++j) a = fmaf(w[k][j], hj[j], a);
        #pragma unroll
        for (int off=32; off; off>>=1) a += __shfl_xor(a, off, 64);
        acc[k] = a;
      }
      if (lane == 0){
        #pragma unroll
        for (int k=0;k<8;++k) sc[wave*8+k] = acc[k];
      }
      __syncthreads();
      if (tid < 16){
        const float ghr = sc[tid]    + br;
        const float ghz = sc[16+tid] + bz;
        const float ghn = sc[32+tid] + bn_;
        const float r = sigmoidf_(gr + ghr);
        const float z = sigmoidf_(gz + ghz);
        const float n = tanhf_(gn + r*ghn);
        const float h = (1.f - z)*n + z*hreg;
        hreg = h;
        st_a64(ring0 + (size_t)(t&(RINGN-1))*512 + mi,
               ((unsigned long long)(unsigned)(t+1)<<32) |
               (unsigned long long)__float_as_uint(h));
        if (t == TSTEPS-1) hnext[mi] = h;
      }
      __syncthreads();
      if (tid == 0){
        __hip_atomic_fetch_add(arr + (size_t)(t&(RINGN-1))*16, 1u,
                               __ATOMIC_RELEASE, __HIP_MEMORY_SCOPE_AGENT);
      }
    }
  } else {
    // ================= layer 1 =================
    const int wgl = wg - G0WG;
    const int ibase = wgl*8;
    const bool isA = (wave < 3);            // waves 0-2: Wih1 (dot h0); waves 3-5: Whh1 (dot h1)
    float w[8][8];
    #pragma unroll
    for (int k=0;k<8;++k){
      const int rid = (isA ? wave : (wave-3))*8 + k;   // 24 rows per half: g = rid>>3, il = rid&7
      const int g = rid>>3, il = rid&7;
      const float* W = isA ? Wih1 : Whh1;
      const float* wp = W + ((size_t)(g*512 + ibase + il))*512;
      #pragma unroll
      for (int j=0;j<8;++j) w[k][j] = wp[j*64 + lane];
    }
    float hreg=0.f, bir=0.f,biz=0.f,bin_=0.f, bhr=0.f,bhz=0.f,bhn=0.f;
    const int mi = ibase + tid;
    if (tid < 8){
      hreg = hprev[512+mi];
      bir = bih1[mi]; biz = bih1[512+mi]; bin_ = bih1[1024+mi];
      bhr = bhh1[mi]; bhz = bhh1[512+mi]; bhn  = bhh1[1024+mi];
    }
    for (int s=0; s<TSTEPS; ++s){
      if (wave == 0){
        spin_to_lds(ring0, s&(RINGN-1), (unsigned)(s+1), lane, hbuf0, &budget);
      } else if (wave == 3){
        if (s == 0){
          #pragma unroll
          for (int j=0;j<8;++j) hbuf1[j*64+lane] = hprev[512 + j*64+lane];
        } else {
          spin_to_lds(ring1, (s-1)&(RINGN-1), (unsigned)s, lane, hbuf1, &budget);
        }
      }
      if (tid==0 && s>=16){
        unsigned* ap = arr + (size_t)((s-16)&(RINGN-1))*16;
        const unsigned expect = (unsigned)NWG_SCAN * (unsigned)(((s-16)>>5)+1);
        while (__hip_atomic_load(ap, __ATOMIC_RELAXED, __HIP_MEMORY_SCOPE_AGENT) < expect){
          if (--budget < 0) break;
        }
      }
      __syncthreads();
      const float* hsrc = isA ? hbuf0 : hbuf1;
      float hj[8];
      #pragma unroll
      for (int j=0;j<8;++j) hj[j] = hsrc[j*64+lane];
      float acc[8];
      #pragma unroll
      for (int k=0;k<8;++k){
        float a = 0.f;
        #pragma unroll
        for (int j=0;j<8;++j) a = fmaf(w[k][j], hj[j], a);
        #pragma unroll
        for (int off=32; off; off>>=1) a += __shfl_xor(a, off, 64);
        acc[k] = a;
      }
      if (lane == 0){
        const int base = isA ? (wave*8) : (24 + (wave-3)*8);
        #pragma unroll
        for (int k=0;k<8;++k) sc[base+k] = acc[k];
      }
      __syncthreads();
      if (tid < 8){
        const float gir = sc[tid]    + bir;
        const float giz = sc[8+tid]  + biz;
        const float gin = sc[16+tid] + bin_;
        const float ghr = sc[24+tid] + bhr;
        const float ghz = sc[32+tid] + bhz;
        const float ghn = sc[40+tid] + bhn;
        const float r = sigmoidf_(gir + ghr);
        const float z = sigmoidf_(giz + ghz);
        const float n = tanhf_(gin + r*ghn);
        const float h = (1.f - z)*n + z*hreg;
        hreg = h;
        st_a64(ring1 + (size_t)(s&(RINGN-1))*512 + mi,
               ((unsigned long long)(unsigned)(s+1)<<32) |
               (unsigned long long)__float_as_uint(h));
        H1hist[(size_t)s*512 + mi] = h;
        if (s == TSTEPS-1) hnext[512+mi] = h;
      }
      __syncthreads();
      if (tid == 0){
        __hip_atomic_fetch_add(arr + (size_t)(s&(RINGN-1))*16, 1u,
                               __ATOMIC_RELEASE, __HIP_MEMORY_SCOPE_AGENT);
      }
    }
  }
}

// ---------------- tiled fp32 GEMM: C[m][n] = sum_k A[m][k]*B[n][k] + bias[n] ----------------
// BM=BN=64, BK=32, 256 threads, 4x4 per thread. EPI=1: relu then mask(n)==0 -> NEG.
template<int EPI>
__global__ __launch_bounds__(256) void gemm_nt(
    const float* __restrict__ A, int lda,
    const float* __restrict__ B, int ldb,
    float* __restrict__ C, int ldc,
    const float* __restrict__ bias,
    const int* __restrict__ mask,
    int K)
{
  __shared__ __align__(16) float As[32][68];
  __shared__ __align__(16) float Bs[32][68];
  const int bm = blockIdx.y*64, bn = blockIdx.x*64;
  const int tid = threadIdx.x;
  const int tm = tid>>4, tn = tid&15;
  float acc[4][4] = {};
  const int m0 = tid>>2, kk0 = (tid&3)*8;
  for (int k0=0; k0<K; k0+=32){
    #pragma unroll
    for (int j=0;j<8;++j) As[kk0+j][m0] = A[(size_t)(bm+m0)*lda + k0+kk0+j];
    #pragma unroll
    for (int j=0;j<8;++j) Bs[kk0+j][m0] = B[(size_t)(bn+m0)*ldb + k0+kk0+j];
    __syncthreads();
    #pragma unroll
    for (int kk=0;kk<32;++kk){
      const float4 av = *(const float4*)&As[kk][tm*4];
      const float4 bv = *(const float4*)&Bs[kk][tn*4];
      acc[0][0]=fmaf(av.x,bv.x,acc[0][0]); acc[0][1]=fmaf(av.x,bv.y,acc[0][1]);
      acc[0][2]=fmaf(av.x,bv.z,acc[0][2]); acc[0][3]=fmaf(av.x,bv.w,acc[0][3]);
      acc[1][0]=fmaf(av.y,bv.x,acc[1][0]); acc[1][1]=fmaf(av.y,bv.y,acc[1][1]);
      acc[1][2]=fmaf(av.y,bv.z,acc[1][2]); acc[1][3]=fmaf(av.y,bv.w,acc[1][3]);
      acc[2][0]=fmaf(av.z,bv.x,acc[2][0]); acc[2][1]=fmaf(av.z,bv.y,acc[2][1]);
      acc[2][2]=fmaf(av.z,bv.z,acc[2][2]); acc[2][3]=fmaf(av.z,bv.w,acc[2][3]);
      acc[3][0]=fmaf(av.w,bv.x,acc[3][0]); acc[3][1]=fmaf(av.w,bv.y,acc[3][1]);
      acc[3][2]=fmaf(av.w,bv.z,acc[3][2]); acc[3][3]=fmaf(av.w,bv.w,acc[3][3]);
    }
    __syncthreads();
  }
  #pragma unroll
  for (int i=0;i<4;++i){
    #pragma unroll
    for (int j=0;j<4;++j){
      const int mm = bm + tm*4 + i, cc = bn + tn*4 + j;
      float v = acc[i][j] + bias[cc];
      if (EPI){
        v = fmaxf(v, 0.f);
        if (mask[cc] == 0) v = NEG_VAL;
      }
      C[(size_t)mm*ldc + cc] = v;
    }
  }
}

// ---------------- launch ----------------
extern "C" void kernel_launch(void* const* d_in, const int* in_sizes, int n_in,
                              void* d_out, int out_size, void* d_ws, size_t ws_size,
                              hipStream_t stream)
{
  const float* state = (const float*)d_in[0];   // (4096, 129)
  const float* hprev = (const float*)d_in[1];   // (2, 512)
  const int*   mask  = (const int*)d_in[2];     // (64, 64)
  const float* Wih0  = (const float*)d_in[3];   // (1536, 128)
  const float* Whh0  = (const float*)d_in[4];   // (1536, 512)
  const float* bih0  = (const float*)d_in[5];
  const float* bhh0  = (const float*)d_in[6];
  const float* Wih1  = (const float*)d_in[7];   // (1536, 512)
  const float* Whh1  = (const float*)d_in[8];   // (1536, 512)
  const float* bih1  = (const float*)d_in[9];
  const float* bhh1  = (const float*)d_in[10];
  const float* Wfc   = (const float*)d_in[11];  // (4096, 512)
  const float* bfc   = (const float*)d_in[12];

  if (ws_size < WS_NEED) return;   // fail loudly via poisoned output

  float* out = (float*)d_out;
  char*  ws  = (char*)d_ws;
  float* gi0 = (float*)(ws + GI0_OFF);
  float* H1  = (float*)(ws + H1_OFF);
  unsigned long long* ring0 = (unsigned long long*)(ws + RING0_OFF);
  unsigned long long* ring1 = (unsigned long long*)(ws + RING1_OFF);
  unsigned* arr = (unsigned*)(ws + ARR_OFF);

  // reset rings + flow counters each call (harness does not re-poison between replays)
  (void)hipMemsetAsync(ws + RING0_OFF, 0, (size_t)(WS_NEED - RING0_OFF), stream);

  // gi0 = x @ Wih0^T + bih0   (M=4096, N=1536, K=128)
  {
    dim3 grid(1536/64, 4096/64);
    gemm_nt<0><<<grid, 256, 0, stream>>>(state+1, 129, Wih0, 128, gi0, 1536,
                                         bih0, nullptr, 128);
  }

  // sequential 2-layer GRU scan
  gru_scan<<<NWG_SCAN, 384, 0, stream>>>(gi0, hprev, Whh0, Wih1, Whh1,
                                         bhh0, bih1, bhh1,
                                         H1, ring0, ring1, arr,
                                         out + (size_t)4096*4096);

  // logits = relu(H1 @ Wfc^T + bfc), masked   (M=4096, N=4096, K=512)
  {
    dim3 grid(4096/64, 4096/64);
    gemm_nt<1><<<grid, 256, 0, stream>>>(H1, 512, Wfc, 512, out, 4096,
                                         bfc, mask, 512);
  }
}